// Round 5
// baseline (1491.348 us; speedup 1.0000x reference)
//
#include <hip/hip_runtime.h>
#include <math.h>

#define BATCH 1024
#define TSEQ  2048
#define DIN   5
#define H     64
#define BT    4      // elems per block; grid 256 = every CU
#define SSTR  144    // halves/elem: [h1 64 | h2 64 | pad 16] -> exact 2-way banks (free)
#define NOUT  128
#define NBUF  4      // state ring depth (G1 leads G2 by up to 3 iters)

typedef _Float16 f16x8 __attribute__((ext_vector_type(8)));
typedef float    f32x4 __attribute__((ext_vector_type(4)));

#if __has_builtin(__builtin_amdgcn_rcpf)
__device__ __forceinline__ float rcp_fast(float x) { return __builtin_amdgcn_rcpf(x); }
#else
__device__ __forceinline__ float rcp_fast(float x) { return 1.0f / x; }
#endif

#define LOG2E 1.44269504088896f
#define MFMA16(A, B, C) __builtin_amdgcn_mfma_f32_16x16x32_f16((A), (B), (C), 0, 0, 0)

// exp2-based activations; weights/biases pre-scaled by log2e (sigmoid) or
// 2*log2e (tanh gate) so no per-use multiply.
__device__ __forceinline__ float sigm2(float s) {   // s = log2e * p
    return rcp_fast(1.0f + __builtin_amdgcn_exp2f(-s));
}
__device__ __forceinline__ float tanh2(float s) {   // s = 2*log2e * p
    return fmaf(-2.0f, rcp_fast(__builtin_amdgcn_exp2f(s) + 1.0f), 1.0f);
}

// ---- LDS flag sync (block-scope; no s_barrier in main loops) ----
// Flags = monotone iteration counters, one per wave slot, read VOLATILE
// (guaranteed ds_read each spin -> poll provably observes the publisher).
// Release: data ds_write -> s_waitcnt lgkmcnt(0) -> flag ds_write.
// Acquire: volatile poll -> memory clobber -> data ds_read.
__device__ __forceinline__ int min4v(volatile const int* fl) {
    int a = fl[0]; int b = fl[1]; int c = fl[2]; int d = fl[3];
    return min(min(a, b), min(c, d));
}
__device__ __forceinline__ void wait_ge(volatile const int* fl, int tgt) {
    while (min4v(fl) < tgt) __builtin_amdgcn_s_sleep(1);
    asm volatile("" ::: "memory");
}
__device__ __forceinline__ void wait2_ge(volatile const int* f1, int t1,
                                         volatile const int* f2, int t2) {
    while (min4v(f1) < t1 || min4v(f2) < t2) __builtin_amdgcn_s_sleep(1);
    asm volatile("" ::: "memory");
}
__device__ __forceinline__ void publish(volatile int* slot, int v, bool lead) {
    asm volatile("s_waitcnt lgkmcnt(0)" ::: "memory");   // data visible first
    __builtin_amdgcn_sched_barrier(0);
    if (lead) *slot = v;
    asm volatile("" ::: "memory");
}

// R5: DECOUPLED WAVE GROUPS (hardened R4). R1-R3 showed the wall is phase
// lockstep (all 8 waves leave one barrier together and burst the same pipe:
// LDS-read burst -> MFMA burst -> trans burst serialize ~1280 cyc/iter).
// Fix: no s_barrier in the main loop. State ring NBUF=4 deep; lay-1 group
// (G1, waves 0-3) runs up to 3 iters ahead of lay-2 group (G2, waves 4-7).
// Phases anti-align across groups; G1's MFMA/gate work fills G2's
// read-latency and gate-chain shadows (and vice versa).
// Protocol (2 flag arrays, deadlock-free by induction; init w1fl=-1, w2fl=0):
//   G1@i: wait min(w1fl)>=i-1 (h1(i-1) complete);
//         wait min(w2fl)>=i-3 before writing h1(i) over h1(i-4) (WAR: G2@i-3
//         read h1(i-4); its completion implies those reads are done).
//   G2@i: wait min(w1fl)>=i-1 (y1(i-1)) and min(w2fl)>=i-1 (h2(i-2));
//         read -> MFMA -> gates -> write h2(i-1) -> publish w2fl=i.
__global__ __launch_bounds__(512)
void lstm_mfma(const float* __restrict__ x,
               const float* __restrict__ Wih0, const float* __restrict__ Whh0,
               const float* __restrict__ bih0, const float* __restrict__ bhh0,
               const float* __restrict__ Wih1, const float* __restrict__ Whh1,
               const float* __restrict__ bih1, const float* __restrict__ bhh1,
               const float* __restrict__ Wfc,  const float* __restrict__ bfc,
               float* __restrict__ out)
{
    __shared__ alignas(16) _Float16 S[NBUF][BT * SSTR];  // 4.5 KB state ring
    __shared__ alignas(16) float    h2f[BT][H];          // 1 KB final h2 for FC
    __shared__ alignas(16) int      flg[8];              // [0:4) w1fl  [4:8) w2fl

    const int tid  = threadIdx.x;
    const int w    = tid >> 6;         // 0..7
    const int lane = tid & 63;
    const int col  = lane & 15;        // n (h-unit offset); A-row m
    const int q    = lane >> 4;        // quad -> C/D row group; k-slice
    const int ww   = w & 3;            // h-unit tile / flag slot
    const int lay  = w >> 2;           // 0 = layer-1 group, 1 = layer-2 group
    const int hu   = 16 * ww + col;
    const int b0   = blockIdx.x * BT;

    // ---- zero state ring; init flags ----
    for (int j = tid; j < NBUF * BT * SSTR; j += 512)
        ((_Float16*)S)[j] = (_Float16)0.0f;
    if (tid < 4)      flg[tid] = -1;   // w1fl: "h1(-1) written" (zeros)
    else if (tid < 8) flg[tid] = 0;    // w2fl: "G2 iter 0 done" (G2 starts at 1)

    const float sgl[4] = {LOG2E, LOG2E, 2.0f * LOG2E, LOG2E};  // i,f,g,o

    // ---- B-fragments for THIS wave's layer (registers, pre-scaled) ----
    f16x8 Bf[4][4];
    f32x4 bC[4];        // lay-2 bias as MFMA C
    float wx[4][DIN];   // lay-1: Wih0 row (pre-scaled), f32
    float b1s[4];       // lay-1 scalar bias
    #pragma unroll
    for (int g = 0; g < 4; ++g) {
        const int   row = g * 64 + hu;
        const float sg  = sgl[g];
        if (lay) {
            const float* wa = Wih1 + row * H;
            const float* wb = Whh1 + row * H;
            #pragma unroll
            for (int j = 0; j < 8; ++j) {
                const int k = q * 8 + j;
                Bf[g][0][j] = (_Float16)(wa[k]      * sg);
                Bf[g][1][j] = (_Float16)(wa[32 + k] * sg);
                Bf[g][2][j] = (_Float16)(wb[k]      * sg);
                Bf[g][3][j] = (_Float16)(wb[32 + k] * sg);
            }
            const float bb = (bih1[row] + bhh1[row]) * sg;
            bC[g] = f32x4{bb, bb, bb, bb};
        } else {
            const float* wh = Whh0 + row * H;
            #pragma unroll
            for (int j = 0; j < 8; ++j) {
                const int k = q * 8 + j;
                Bf[g][0][j] = (_Float16)(wh[k]      * sg);
                Bf[g][1][j] = (_Float16)(wh[32 + k] * sg);
            }
            #pragma unroll
            for (int j = 0; j < DIN; ++j)
                wx[g][j] = Wih0[row * DIN + j] * sg;
            b1s[g] = (bih0[row] + bhh0[row]) * sg;
        }
    }

    // ---- x pipeline (G1): dxs(t) ready at iter t; regs carry x(t+1) ----
    const float* xq = x + (size_t)(b0 + q) * TSEQ * DIN;
    float x0 = 0.f, x1 = 0.f, x2 = 0.f, x3 = 0.f, x4 = 0.f;
    float dxs[4] = {0.f, 0.f, 0.f, 0.f};
    if (lay == 0) {
        float a0 = xq[0], a1 = xq[1], a2 = xq[2], a3 = xq[3], a4 = xq[4];
        #pragma unroll
        for (int g = 0; g < 4; ++g) {
            float s = fmaf(a0, wx[g][0], b1s[g]);
            s = fmaf(a1, wx[g][1], s);
            s = fmaf(a2, wx[g][2], s);
            s = fmaf(a3, wx[g][3], s);
            dxs[g] = fmaf(a4, wx[g][4], s);
        }
        x0 = xq[DIN + 0]; x1 = xq[DIN + 1]; x2 = xq[DIN + 2];
        x3 = xq[DIN + 3]; x4 = xq[DIN + 4];
        xq += 2 * DIN;      // -> t=2
    }

    const int ab  = (col >> 2) * SSTR + q * 8;   // A-frag read base (halves)
    const int wb1 = q * SSTR + hu;               // h1 write slot
    const int wb2 = q * SSTR + 64 + hu;          // h2 write slot
    float cst = 0.0f, h2fin = 0.0f;

    volatile int* w1fl = flg;
    volatile int* w2fl = flg + 4;

    __syncthreads();   // zeros + flags visible; last block-wide sync until FC

    if (lay == 0) {
        // ================= G1: layer-1, iters 0..TSEQ-1 =================
        #pragma unroll 1
        for (int i = 0; i < TSEQ; ++i) {
            const _Float16* rb   = S[(i + 3) & 3];
            _Float16*       wbuf = S[i & 3];

            const bool ld2 = (i + 2 < TSEQ);
            float n0, n1, n2, n3, n4;
            if (ld2) { n0 = xq[0]; n1 = xq[1]; n2 = xq[2]; n3 = xq[3]; n4 = xq[4]; xq += DIN; }

            wait_ge(w1fl, i - 1);                    // h1(i-1) written by all G1

            f16x8 a0 = *(const f16x8*)&rb[ab];       // h1(i-1) k 0..31
            f16x8 a1 = *(const f16x8*)&rb[ab + 32];  // h1(i-1) k 32..63

            f32x4 d[4];
            __builtin_amdgcn_s_setprio(1);
            #pragma unroll
            for (int g = 0; g < 4; ++g) {            // 2-deep chains, 4-way ILP
                f32x4 c0 = {dxs[g], 0.f, 0.f, 0.f};  // only D row 4q (elem q) is read
                d[g] = MFMA16(a0, Bf[g][0], c0);
                d[g] = MFMA16(a1, Bf[g][1], d[g]);
            }
            __builtin_amdgcn_s_setprio(0);

            float iv = sigm2(d[0][0]);
            float fv = sigm2(d[1][0]);
            float gv = tanh2(d[2][0]);
            float ov = sigm2(d[3][0]);
            cst = fmaf(fv, cst, iv * gv);
            const float hval = ov * tanh2(2.0f * LOG2E * cst);

            // dxs(i+1) off the critical path (x regs hold x(i+1))
            if (i + 1 < TSEQ) {
                #pragma unroll
                for (int g = 0; g < 4; ++g) {
                    float s = fmaf(x0, wx[g][0], b1s[g]);
                    s = fmaf(x1, wx[g][1], s);
                    s = fmaf(x2, wx[g][2], s);
                    s = fmaf(x3, wx[g][3], s);
                    dxs[g] = fmaf(x4, wx[g][4], s);
                }
            }
            if (ld2) { x0 = n0; x1 = n1; x2 = n2; x3 = n3; x4 = n4; }

            wait_ge(w2fl, i - 3);                    // WAR: G2@(i-3) fully done
            wbuf[wb1] = (_Float16)hval;
            publish(&w1fl[ww], i, lane == 0);
        }
    } else {
        // ============ G2: layer-2, iters 1..TSEQ (computes h2(i-1)) ============
        #pragma unroll 1
        for (int i = 1; i <= TSEQ; ++i) {
            const _Float16* rb   = S[(i + 3) & 3];
            _Float16*       wbuf = S[i & 3];

            wait2_ge(w1fl, i - 1, w2fl, i - 1);      // y1(i-1) & h2(i-2) ready

            f16x8 ay0 = *(const f16x8*)&rb[ab];        // y1(i-1) k 0..31
            f16x8 ay1 = *(const f16x8*)&rb[ab + 32];   // y1(i-1) k 32..63
            f16x8 ah0 = *(const f16x8*)&rb[ab + 64];   // h2(i-2) k 0..31
            f16x8 ah1 = *(const f16x8*)&rb[ab + 96];   // h2(i-2) k 32..63

            f32x4 e[4], f[4];
            const f32x4 z4 = {0.f, 0.f, 0.f, 0.f};
            __builtin_amdgcn_s_setprio(1);
            #pragma unroll
            for (int g = 0; g < 4; ++g) {            // 8 chains, all 2-deep
                e[g] = MFMA16(ay0, Bf[g][0], bC[g]);
                e[g] = MFMA16(ay1, Bf[g][1], e[g]);
                f[g] = MFMA16(ah0, Bf[g][2], z4);
                f[g] = MFMA16(ah1, Bf[g][3], f[g]);
            }
            __builtin_amdgcn_s_setprio(0);

            float p0 = e[0][0] + f[0][0];
            float p1 = e[1][0] + f[1][0];
            float p2 = e[2][0] + f[2][0];
            float p3 = e[3][0] + f[3][0];
            float iv = sigm2(p0);
            float fv = sigm2(p1);
            float gv = tanh2(p2);
            float ov = sigm2(p3);
            cst = fmaf(fv, cst, iv * gv);
            h2fin = ov * tanh2(2.0f * LOG2E * cst);

            wbuf[wb2] = (_Float16)h2fin;
            publish(&w2fl[ww], i, lane == 0);
        }
    }

    // ---------------- epilogue: out = relu(h2(T-1) @ Wfc^T + bfc) ----------------
    if (lay) h2f[q][hu] = h2fin;
    __syncthreads();
    {
        const int e = tid >> 7;            // 0..3
        const int o = tid & (NOUT - 1);    // 0..127
        const float4* wr = (const float4*)(Wfc + o * H);
        const float*  hv = h2f[e];
        float s0 = 0.f, s1 = 0.f, s2 = 0.f, s3 = 0.f;
        #pragma unroll
        for (int k = 0; k < H / 4; ++k) {
            float4 wv = wr[k];
            s0 = fmaf(wv.x, hv[4 * k + 0], s0);
            s1 = fmaf(wv.y, hv[4 * k + 1], s1);
            s2 = fmaf(wv.z, hv[4 * k + 2], s2);
            s3 = fmaf(wv.w, hv[4 * k + 3], s3);
        }
        float acc = bfc[o] + (s0 + s1) + (s2 + s3);
        out[(size_t)(b0 + e) * NOUT + o] = fmaxf(acc, 0.0f);
    }
}

extern "C" void kernel_launch(void* const* d_in, const int* in_sizes, int n_in,
                              void* d_out, int out_size, void* d_ws, size_t ws_size,
                              hipStream_t stream) {
    const float* x    = (const float*)d_in[0];
    const float* Wih0 = (const float*)d_in[1];
    const float* Whh0 = (const float*)d_in[2];
    const float* bih0 = (const float*)d_in[3];
    const float* bhh0 = (const float*)d_in[4];
    const float* Wih1 = (const float*)d_in[5];
    const float* Whh1 = (const float*)d_in[6];
    const float* bih1 = (const float*)d_in[7];
    const float* bhh1 = (const float*)d_in[8];
    const float* Wfc  = (const float*)d_in[9];
    const float* bfc  = (const float*)d_in[10];
    float* out = (float*)d_out;

    lstm_mfma<<<dim3(BATCH / BT), dim3(512), 0, stream>>>(
        x, Wih0, Whh0, bih0, bhh0, Wih1, Whh1, bih1, bhh1, Wfc, bfc, out);
}

// Round 6
// 1214.985 us; speedup vs baseline: 1.2275x; 1.2275x over previous
//
#include <hip/hip_runtime.h>
#include <math.h>

#define BATCH 1024
#define TSEQ  2048
#define DIN   5
#define H     64
#define BT    4      // elems per block; grid 256 = every CU
#define SSTR  144    // halves/elem: [h1 64 | h2 64 | pad 16] -> exact 2-way banks (free)
#define NOUT  128

typedef _Float16 f16x8 __attribute__((ext_vector_type(8)));
typedef float    f32x4 __attribute__((ext_vector_type(4)));

#if __has_builtin(__builtin_amdgcn_rcpf)
__device__ __forceinline__ float rcp_fast(float x) { return __builtin_amdgcn_rcpf(x); }
#else
__device__ __forceinline__ float rcp_fast(float x) { return 1.0f / x; }
#endif

#define LOG2E 1.44269504088896f
#define MFMA16(A, B, C) __builtin_amdgcn_mfma_f32_16x16x32_f16((A), (B), (C), 0, 0, 0)

// exp2-based activations; weights/biases pre-scaled by log2e (sigmoid) or
// 2*log2e (tanh gate) so no per-use multiply.
__device__ __forceinline__ float sigm2(float s) {   // s = log2e * p
    return rcp_fast(1.0f + __builtin_amdgcn_exp2f(-s));
}
__device__ __forceinline__ float tanh2(float s) {   // s = 2*log2e * p
    return fmaf(-2.0f, rcp_fast(__builtin_amdgcn_exp2f(s) + 1.0f), 1.0f);
}

// lgkm-only barrier: ds_write visibility without draining vmcnt (x loads
// stay in flight across the barrier; compiler counts vmcnt at the use).
__device__ __forceinline__ void sync_lgkm() {
    asm volatile("s_waitcnt lgkmcnt(0)" ::: "memory");
    __builtin_amdgcn_s_barrier();
    asm volatile("" ::: "memory");
}

// R6: E-OFFLOAD + LAG-2 LAYER-2 (barrier lockstep retained — R5 proved LDS
// flag-polling costs more than s_barrier).
// Mechanism: G1's A-fragments a0/a1 = h1(i-1) = y1(i-1) are ALSO the input
// of layer-2's y1-partial. G1 computes e(i-1) = bias2 + Wih1*y1(i-1) with
// ZERO extra LDS reads (8 extra MFMAs in its gate-chain shadow) and stages
// e[g][0] (16B/lane) to LDS. G2 runs at lag 2 (computes h2(i-2) at interval
// i): reads h2(i-3) (2xb128) + staged e(i-2) (1xb128), does 8 MFMAs instead
// of 16, adds, gates, writes. Per-SIMD MFMA stays 24; the critical wave's
// post-barrier chain loses 1 read + half its MFMA pipe share.
// Lag bookkeeping (loop i = 0..TSEQ+1, 2050 barriers for all waves):
//   G1@i: d-step t=i if i<TSEQ (reads h1(i-1), writes h1(i));
//         e(i-1) if 1<=i<=TSEQ (same a0/a1), writes E[i&1].
//   G2@i (i>=2): h2(i-2) = gates(e(i-2)[E[(i+1)&1]] + Whh1*h2(i-3)[S ring]).
__global__ __launch_bounds__(512, 2)
void lstm_mfma(const float* __restrict__ x,
               const float* __restrict__ Wih0, const float* __restrict__ Whh0,
               const float* __restrict__ bih0, const float* __restrict__ bhh0,
               const float* __restrict__ Wih1, const float* __restrict__ Whh1,
               const float* __restrict__ bih1, const float* __restrict__ bhh1,
               const float* __restrict__ Wfc,  const float* __restrict__ bfc,
               float* __restrict__ out)
{
    __shared__ alignas(16) _Float16 S[2][BT * SSTR];   // 2.25 KB state, double-buffered
    __shared__ alignas(16) float    h2f[BT][H];        // 1 KB final h2 for FC
    __shared__ alignas(16) float4   E[2][4][64];       // 8 KB e-stage [buf][ww][lane]

    const int tid  = threadIdx.x;
    const int w    = tid >> 6;         // 0..7
    const int lane = tid & 63;
    const int col  = lane & 15;        // n (h-unit offset); A-row m
    const int q    = lane >> 4;        // quad -> C/D row group; k-slice
    const int ww   = w & 3;            // h-unit tile
    const int lay  = w >> 2;           // 0 = layer-1 group, 1 = layer-2 group
    const int hu   = 16 * ww + col;
    const int b0   = blockIdx.x * BT;

    // ---- zero both state buffers (E needs no init: first read i=2 hits
    //      E[1], written at i=1) ----
    for (int j = tid; j < 2 * BT * SSTR; j += 512)
        ((_Float16*)S)[j] = (_Float16)0.0f;

    const float sgl[4] = {LOG2E, LOG2E, 2.0f * LOG2E, LOG2E};  // i,f,g,o

    // ---- B-fragments (registers, pre-scaled) ----
    // G1: Bf=Whh0 (d-chain), Cf=Wih1 (e-chain), bC2=layer-2 bias, wx/b1s=x-proj
    // G2: Bf=Whh1 (f-chain)
    f16x8 Bf[4][2];
    f16x8 Cf[4][2];
    f32x4 bC2[4];
    float wx[4][DIN];
    float b1s[4];
    #pragma unroll
    for (int g = 0; g < 4; ++g) {
        const int   row = g * 64 + hu;
        const float sg  = sgl[g];
        if (lay) {
            const float* wb = Whh1 + row * H;
            #pragma unroll
            for (int j = 0; j < 8; ++j) {
                const int k = q * 8 + j;
                Bf[g][0][j] = (_Float16)(wb[k]      * sg);
                Bf[g][1][j] = (_Float16)(wb[32 + k] * sg);
            }
        } else {
            const float* wh = Whh0 + row * H;
            const float* wi = Wih1 + row * H;
            #pragma unroll
            for (int j = 0; j < 8; ++j) {
                const int k = q * 8 + j;
                Bf[g][0][j] = (_Float16)(wh[k]      * sg);
                Bf[g][1][j] = (_Float16)(wh[32 + k] * sg);
                Cf[g][0][j] = (_Float16)(wi[k]      * sg);
                Cf[g][1][j] = (_Float16)(wi[32 + k] * sg);
            }
            #pragma unroll
            for (int j = 0; j < DIN; ++j)
                wx[g][j] = Wih0[row * DIN + j] * sg;
            b1s[g] = (bih0[row] + bhh0[row]) * sg;
            const float bb2 = (bih1[row] + bhh1[row]) * sg;
            bC2[g] = f32x4{bb2, bb2, bb2, bb2};
        }
    }

    // ---- x pipeline (G1): dxs(t) ready at iter t; regs carry x(t+1) ----
    const float* xq = x + (size_t)(b0 + q) * TSEQ * DIN;
    float x0 = 0.f, x1 = 0.f, x2 = 0.f, x3 = 0.f, x4 = 0.f;
    float dxs[4] = {0.f, 0.f, 0.f, 0.f};
    if (lay == 0) {
        float a0 = xq[0], a1 = xq[1], a2 = xq[2], a3 = xq[3], a4 = xq[4];
        #pragma unroll
        for (int g = 0; g < 4; ++g) {
            float s = fmaf(a0, wx[g][0], b1s[g]);
            s = fmaf(a1, wx[g][1], s);
            s = fmaf(a2, wx[g][2], s);
            s = fmaf(a3, wx[g][3], s);
            dxs[g] = fmaf(a4, wx[g][4], s);
        }
        x0 = xq[DIN + 0]; x1 = xq[DIN + 1]; x2 = xq[DIN + 2];
        x3 = xq[DIN + 3]; x4 = xq[DIN + 4];
        xq += 2 * DIN;      // -> t=2
    }

    const int ab  = (col >> 2) * SSTR + q * 8;   // A-frag read base (halves)
    const int wb1 = q * SSTR + hu;               // h1 write slot
    const int wb2 = q * SSTR + 64 + hu;          // h2 write slot
    float cst = 0.0f, h2fin = 0.0f;

    __syncthreads();

    // ========= main loop: 2050 intervals (lag-2 layer-2 needs TSEQ+2) =========
    #pragma unroll 1
    for (int i = 0; i <= TSEQ + 1; ++i) {
        const _Float16* rb   = S[(i + 1) & 1];
        _Float16*       wbuf = S[i & 1];

        if (lay == 0) {
            const bool dact = (i < TSEQ);                 // lay-1 step t=i
            const bool eact = (i >= 1) && (i <= TSEQ);    // e(i-1)
            const bool ld2  = (i + 2 < TSEQ);
            float n0, n1, n2, n3, n4;
            if (ld2) { n0 = xq[0]; n1 = xq[1]; n2 = xq[2]; n3 = xq[3]; n4 = xq[4]; xq += DIN; }

            f16x8 a0, a1;
            if (dact || eact) {
                a0 = *(const f16x8*)&rb[ab];        // h1(i-1) = y1(i-1), k 0..31
                a1 = *(const f16x8*)&rb[ab + 32];   // k 32..63
            }

            f32x4 d[4], e[4];
            __builtin_amdgcn_s_setprio(1);
            if (dact) {
                #pragma unroll
                for (int g = 0; g < 4; ++g) {            // 2-deep chains, 4-way ILP
                    f32x4 c0 = {dxs[g], 0.f, 0.f, 0.f};  // only D row 4q (elem q) read
                    d[g] = MFMA16(a0, Bf[g][0], c0);
                    d[g] = MFMA16(a1, Bf[g][1], d[g]);
                }
            }
            if (eact) {
                #pragma unroll
                for (int g = 0; g < 4; ++g) {            // e-chain fills d's latency
                    e[g] = MFMA16(a0, Cf[g][0], bC2[g]);
                    e[g] = MFMA16(a1, Cf[g][1], e[g]);
                }
            }
            __builtin_amdgcn_s_setprio(0);

            if (dact) {   // layer-1 gates for t=i
                float iv = sigm2(d[0][0]);
                float fv = sigm2(d[1][0]);
                float gv = tanh2(d[2][0]);
                float ov = sigm2(d[3][0]);
                cst = fmaf(fv, cst, iv * gv);
                wbuf[wb1] = (_Float16)(ov * tanh2(2.0f * LOG2E * cst));
            }
            // dxs(i+1) off the critical path (x regs hold x(i+1))
            if (i + 1 < TSEQ) {
                #pragma unroll
                for (int g = 0; g < 4; ++g) {
                    float s = fmaf(x0, wx[g][0], b1s[g]);
                    s = fmaf(x1, wx[g][1], s);
                    s = fmaf(x2, wx[g][2], s);
                    s = fmaf(x3, wx[g][3], s);
                    dxs[g] = fmaf(x4, wx[g][4], s);
                }
            }
            if (ld2) { x0 = n0; x1 = n1; x2 = n2; x3 = n3; x4 = n4; }
            if (eact)
                E[i & 1][ww][lane] = float4{e[0][0], e[1][0], e[2][0], e[3][0]};
        } else if (i >= 2) {
            // layer-2 step t=i-2: e(i-2) staged by G1 at interval i-1;
            // h2(i-3) written by G2 at interval i-1.
            f16x8 ah0 = *(const f16x8*)&rb[ab + 64];   // h2(i-3) k 0..31
            f16x8 ah1 = *(const f16x8*)&rb[ab + 96];   // h2(i-3) k 32..63
            float4 er = E[(i + 1) & 1][ww][lane];      // e(i-2), 4 gates

            f32x4 f[4];
            const f32x4 z4 = {0.f, 0.f, 0.f, 0.f};
            __builtin_amdgcn_s_setprio(1);
            #pragma unroll
            for (int g = 0; g < 4; ++g) {              // 4 chains, 2-deep
                f[g] = MFMA16(ah0, Bf[g][0], z4);
                f[g] = MFMA16(ah1, Bf[g][1], f[g]);
            }
            __builtin_amdgcn_s_setprio(0);

            float p0 = er.x + f[0][0];
            float p1 = er.y + f[1][0];
            float p2 = er.z + f[2][0];
            float p3 = er.w + f[3][0];
            float iv = sigm2(p0);
            float fv = sigm2(p1);
            float gv = tanh2(p2);
            float ov = sigm2(p3);
            cst = fmaf(fv, cst, iv * gv);
            h2fin = ov * tanh2(2.0f * LOG2E * cst);
            wbuf[wb2] = (_Float16)h2fin;
        }
        sync_lgkm();
    }

    // ---------------- epilogue: out = relu(h2(T-1) @ Wfc^T + bfc) ----------------
    if (lay) h2f[q][hu] = h2fin;
    __syncthreads();
    {
        const int e = tid >> 7;            // 0..3
        const int o = tid & (NOUT - 1);    // 0..127
        const float4* wr = (const float4*)(Wfc + o * H);
        const float*  hv = h2f[e];
        float s0 = 0.f, s1 = 0.f, s2 = 0.f, s3 = 0.f;
        #pragma unroll
        for (int k = 0; k < H / 4; ++k) {
            float4 wv = wr[k];
            s0 = fmaf(wv.x, hv[4 * k + 0], s0);
            s1 = fmaf(wv.y, hv[4 * k + 1], s1);
            s2 = fmaf(wv.z, hv[4 * k + 2], s2);
            s3 = fmaf(wv.w, hv[4 * k + 3], s3);
        }
        float acc = bfc[o] + (s0 + s1) + (s2 + s3);
        out[(size_t)(b0 + e) * NOUT + o] = fmaxf(acc, 0.0f);
    }
}

extern "C" void kernel_launch(void* const* d_in, const int* in_sizes, int n_in,
                              void* d_out, int out_size, void* d_ws, size_t ws_size,
                              hipStream_t stream) {
    const float* x    = (const float*)d_in[0];
    const float* Wih0 = (const float*)d_in[1];
    const float* Whh0 = (const float*)d_in[2];
    const float* bih0 = (const float*)d_in[3];
    const float* bhh0 = (const float*)d_in[4];
    const float* Wih1 = (const float*)d_in[5];
    const float* Whh1 = (const float*)d_in[6];
    const float* bih1 = (const float*)d_in[7];
    const float* bhh1 = (const float*)d_in[8];
    const float* Wfc  = (const float*)d_in[9];
    const float* bfc  = (const float*)d_in[10];
    float* out = (float*)d_out;

    lstm_mfma<<<dim3(BATCH / BT), dim3(512), 0, stream>>>(
        x, Wih0, Whh0, bih0, bhh0, Wih1, Whh1, bih1, bhh1, Wfc, bfc, out);
}